// Round 6
// baseline (479.363 us; speedup 1.0000x reference)
//
#include <hip/hip_runtime.h>
#include <stdint.h>
#include <math.h>

#define B_   16
#define T_   50
#define C_   200
#define N_   10000      // T_*C_
#define NT_  160000     // B_*N_
#define H_   8
#define E_   5120000
#define EPS_ 1e-5f
#define NB_  625        // CSR buckets: dst>>8
#define EB_  256        // edge blocks for hist/append
#define EPB_ 20000      // edges per block (E_/EB_)
#define GB_  40         // chunks per graph (gat/pool)
#define GC_  250        // nodes per chunk (N_/GB_)
#define JC_  5          // column chunks per perm tile
#define JW_  40         // columns per chunk
#define ROWP_ 41        // padded LDS row stride (2-way max on 32 banks = free)
#define LOG2E_ 1.44269504088896340736f

// ---------------- Threefry-2x32 (JAX) ----------------
struct TF2C { unsigned a, b; };
constexpr unsigned rotl32c(unsigned v, int r){ return (v << r) | (v >> (32 - r)); }
constexpr TF2C tf_const(unsigned k0, unsigned k1, unsigned x0, unsigned x1){
  unsigned ks2 = k0 ^ k1 ^ 0x1BD11BDAu;
  unsigned ks[3] = {k0, k1, ks2};
  x0 += k0; x1 += k1;
  const int RA[4] = {13, 15, 26, 6};
  const int RB[4] = {17, 29, 16, 24};
  for (int g = 0; g < 5; ++g){
    for (int r = 0; r < 4; ++r){
      int rr = (g & 1) ? RB[r] : RA[r];
      x0 += x1; x1 = rotl32c(x1, rr); x1 ^= x0;
    }
    x0 += ks[(g + 1) % 3];
    x1 += ks[(g + 2) % 3] + (unsigned)(g + 1);
  }
  return TF2C{x0, x1};
}
constexpr TF2C KG = tf_const(0u, 42u, 0u, 0u);
constexpr TF2C KN = tf_const(0u, 42u, 0u, 1u);

__device__ __forceinline__ void tf2(unsigned k0, unsigned k1, unsigned x0, unsigned x1,
                                    unsigned &o0, unsigned &o1){
  unsigned ks2 = k0 ^ k1 ^ 0x1BD11BDAu;
  x0 += k0; x1 += k1;
#define TFR_(R) { x0 += x1; x1 = __builtin_rotateleft32(x1, R); x1 ^= x0; }
  TFR_(13) TFR_(15) TFR_(26) TFR_(6)  x0 += k1;  x1 += ks2 + 1u;
  TFR_(17) TFR_(29) TFR_(16) TFR_(24) x0 += ks2; x1 += k0 + 2u;
  TFR_(13) TFR_(15) TFR_(26) TFR_(6)  x0 += k0;  x1 += k1 + 3u;
  TFR_(17) TFR_(29) TFR_(16) TFR_(24) x0 += k1;  x1 += ks2 + 4u;
  TFR_(13) TFR_(15) TFR_(26) TFR_(6)  x0 += ks2; x1 += k0 + 5u;
#undef TFR_
  o0 = x0; o1 = x1;
}
__device__ __forceinline__ unsigned rbits(unsigned ka, unsigned kb, unsigned m){
  unsigned a, b; tf2(ka, kb, 0u, m, a, b); return a ^ b;
}

__device__ __forceinline__ float erfinv_xla(float x){
  float w = -log1pf(-x * x);
  float p;
  if (w < 5.0f){
    w = w - 2.5f;
    p = 2.81022636e-08f;
    p = fmaf(p, w, 3.43273939e-07f);
    p = fmaf(p, w, -3.5233877e-06f);
    p = fmaf(p, w, -4.39150654e-06f);
    p = fmaf(p, w, 0.00021858087f);
    p = fmaf(p, w, -0.00125372503f);
    p = fmaf(p, w, -0.00417768164f);
    p = fmaf(p, w, 0.246640727f);
    p = fmaf(p, w, 1.50140941f);
  } else {
    w = sqrtf(w) - 3.0f;
    p = -0.000200214257f;
    p = fmaf(p, w, 0.000100950558f);
    p = fmaf(p, w, 0.00134934322f);
    p = fmaf(p, w, -0.00367342844f);
    p = fmaf(p, w, 0.00573950773f);
    p = fmaf(p, w, -0.0076224613f);
    p = fmaf(p, w, 0.00943887047f);
    p = fmaf(p, w, 1.00167406f);
    p = fmaf(p, w, 2.83297682f);
  }
  return p * x;
}

// ---------------- CSR build: atomic-free placement ----------------
__global__ __launch_bounds__(256)
void k_hist(const int* __restrict__ dst, int* __restrict__ cnt){
  __shared__ int h[NB_];
  int tid = threadIdx.x, blk = blockIdx.x;
  for (int i = tid; i < NB_; i += 256) h[i] = 0;
  __syncthreads();
  int e0 = blk * EPB_;
  for (int i = tid; i < EPB_; i += 256)
    atomicAdd(&h[dst[e0 + i] >> 8], 1);
  __syncthreads();
  for (int i = tid; i < NB_; i += 256) cnt[blk * NB_ + i] = h[i];
}

__global__ __launch_bounds__(256)
void k_sumb(const int* __restrict__ cnt, int* __restrict__ bsum){
  __shared__ int sred[4];
  int b = blockIdx.x, tid = threadIdx.x;
  int v = cnt[tid * NB_ + b];
#pragma unroll
  for (int s = 32; s >= 1; s >>= 1) v += __shfl_xor(v, s, 64);
  int w = tid >> 6, l = tid & 63;
  if (l == 0) sred[w] = v;
  __syncthreads();
  if (tid == 0) bsum[b] = sred[0] + sred[1] + sred[2] + sred[3];
}

__global__ void k_scanb(const int* __restrict__ bsum, int* __restrict__ boff){
  __shared__ int ts[256];
  int tid = threadIdx.x;
  int i0 = tid * 3;
  int c0 = (i0 + 0 < NB_) ? bsum[i0 + 0] : 0;
  int c1 = (i0 + 1 < NB_) ? bsum[i0 + 1] : 0;
  int c2 = (i0 + 2 < NB_) ? bsum[i0 + 2] : 0;
  int s = c0 + c1 + c2;
  ts[tid] = s;
  __syncthreads();
  for (int d = 1; d < 256; d <<= 1){
    int t = (tid >= d) ? ts[tid - d] : 0;
    __syncthreads();
    ts[tid] += t;
    __syncthreads();
  }
  int run = ts[tid] - s;
  if (i0 + 0 <= NB_){ boff[i0 + 0] = run; run += c0; }
  if (i0 + 1 <= NB_){ boff[i0 + 1] = run; run += c1; }
  if (i0 + 2 <= NB_){ boff[i0 + 2] = run; run += c2; }
}

__global__ __launch_bounds__(256)
void k_scanc(const int* __restrict__ cnt, const int* __restrict__ boff,
             int* __restrict__ gscan){
  __shared__ int ts[256];
  int b = blockIdx.x, tid = threadIdx.x;
  int v = cnt[tid * NB_ + b];
  ts[tid] = v;
  __syncthreads();
  for (int d = 1; d < 256; d <<= 1){
    int t = (tid >= d) ? ts[tid - d] : 0;
    __syncthreads();
    ts[tid] += t;
    __syncthreads();
  }
  gscan[tid * NB_ + b] = boff[b] + ts[tid] - v;
}

__global__ __launch_bounds__(256)
void k_append(const int* __restrict__ src, const int* __restrict__ dst,
              const int* __restrict__ gscan, unsigned* __restrict__ ebuf){
  __shared__ int gb[NB_];
  __shared__ int lc[NB_];
  int tid = threadIdx.x, blk = blockIdx.x;
  for (int i = tid; i < NB_; i += 256){ gb[i] = gscan[blk * NB_ + i]; lc[i] = 0; }
  __syncthreads();
  int e0 = blk * EPB_;
  for (int i = tid; i < EPB_; i += 256){
    int e = e0 + i;
    int d = dst[e];
    int b = d >> 8;
    int r = atomicAdd(&lc[b], 1);
    ebuf[gb[b] + r] = ((unsigned)src[e] << 8) | (unsigned)(d & 255);
  }
}

// one workgroup per bucket: exact per-node offsets + in-bucket scatter (u16 local src)
__global__ __launch_bounds__(256)
void k_bcsr(const int* __restrict__ boff, const unsigned* __restrict__ ebuf,
            int* __restrict__ offs, unsigned short* __restrict__ srcs16){
  __shared__ int cnt[256];
  __shared__ int ts[256];
  int b = blockIdx.x, tid = threadIdx.x;
  int e0 = boff[b], e1 = boff[b + 1];
  cnt[tid] = 0;
  __syncthreads();
  for (int e = e0 + tid; e < e1; e += 256)
    atomicAdd(&cnt[ebuf[e] & 255u], 1);
  __syncthreads();
  int v = cnt[tid];
  ts[tid] = v;
  __syncthreads();
  for (int d = 1; d < 256; d <<= 1){
    int t = (tid >= d) ? ts[tid - d] : 0;
    __syncthreads();
    ts[tid] += t;
    __syncthreads();
  }
  int excl = ts[tid] - v;
  offs[b * 256 + tid] = e0 + excl;
  __syncthreads();
  cnt[tid] = excl;
  __syncthreads();
  for (int e = e0 + tid; e < e1; e += 256){
    unsigned pk = ebuf[e];
    int dl = (int)(pk & 255u);
    int node = b * 256 + dl;
    int g = node / N_;                       // graphs are N_-aligned, buckets are not
    int pos = e0 + atomicAdd(&cnt[dl], 1);
    srcs16[pos] = (unsigned short)((int)(pk >> 8) - g * N_);
  }
  if (b == 0 && tid == 0) offs[NT_] = E_;
}

// ---------------- permutation layer ----------------
// ez = exp(W + gumbel) = exp(W) / t, t = -log(u).  512 threads -> 32 waves/CU.
__global__ __launch_bounds__(512, 8)
void k_perm(const float* __restrict__ W, const float* __restrict__ x,
            float* __restrict__ ypart){
  __shared__ float ez[C_ * ROWP_];          // 32.8 KB
  __shared__ float Ssh[JW_];
  __shared__ float rs[JW_];

  const int bid = blockIdx.x;               // tb*JC_ + jc
  const int tb = bid / JC_;
  const int jc = bid - tb * JC_;
  const int t = tb / B_;
  const int b = tb - t * B_;
  const int j0 = jc * JW_;
  const int xoff = (b * T_ + t) * C_;
  const int tid = threadIdx.x;
  const int w = tid >> 6, l = tid & 63;
  const size_t wbase = (size_t)tb * (C_ * C_);

  // stage ez = exp(W)/(-log(u))
  for (int e = tid; e < C_ * JW_; e += 512){
    int i = e / JW_;
    int jj = e - i * JW_;
    unsigned m = (unsigned)(tb * (C_ * C_) + i * C_ + j0 + jj);
    unsigned bits = rbits(KG.a, KG.b, m);
    float f = __uint_as_float((bits >> 9) | 0x3f800000u) - 1.0f;   // [0,1) exact
    float tneg;
    if (f >= 0.875f){
      float d = 1.0f - f;                  // exact (Sterbenz)
      float p = 0.16666667f;               // -log(1-d) = d*(1+d/2+...+d^5/6)
      p = fmaf(p, d, 0.2f);
      p = fmaf(p, d, 0.25f);
      p = fmaf(p, d, 0.33333333f);
      p = fmaf(p, d, 0.5f);
      p = fmaf(p, d, 1.0f);
      tneg = d * p;
    } else {
      float u = fmaxf(1e-10f, f + 1e-10f); // uniform(1e-10, 1)
      tneg = -__logf(u);
    }
    float Wv = W[wbase + (size_t)(i * C_ + j0 + jj)];
    ez[i * ROWP_ + jj] = __expf(Wv) * __builtin_amdgcn_rcpf(tneg);
  }
  __syncthreads();

  // column sums (over rows i), 5 columns per wave (8 waves)
#pragma unroll
  for (int q = 0; q < 5; ++q){
    int jj = w * 5 + q;
    float s = ez[l * ROWP_ + jj] + ez[(l + 64) * ROWP_ + jj] + ez[(l + 128) * ROWP_ + jj]
            + ((l < 8) ? ez[(l + 192) * ROWP_ + jj] : 0.f);
#pragma unroll
    for (int sh = 32; sh >= 1; sh >>= 1) s += __shfl_xor(s, sh, 64);
    if (l == 0) Ssh[jj] = s;
  }
  __syncthreads();
  if (tid < JW_) rs[tid] = x[xoff + j0 + tid] / Ssh[tid];
  __syncthreads();

  // per-row partial y
  if (tid < C_){
    float acc = 0.f;
#pragma unroll 8
    for (int jj = 0; jj < JW_; ++jj)
      acc = fmaf(ez[tid * ROWP_ + jj], rs[jj], acc);
    ypart[jc * NT_ + xoff + tid] = acc;
  }
}

// combine 5 column-chunk partials -> y, plus nonzero stats partials
__global__ __launch_bounds__(256)
void k_ycomb(const float* __restrict__ ypart, float* __restrict__ y,
             float* __restrict__ spart){
  __shared__ float sred[12];
  int n = blockIdx.x * 256 + threadIdx.x;
  float v = 0.f;
#pragma unroll
  for (int jc = 0; jc < JC_; ++jc) v += ypart[jc * NT_ + n];
  y[n] = v;
  float s = 0.f, c = 0.f, q = 0.f;
  if (v != 0.f){ s = v; c = 1.f; q = v * v; }
#pragma unroll
  for (int sh = 32; sh >= 1; sh >>= 1){
    s += __shfl_xor(s, sh, 64);
    c += __shfl_xor(c, sh, 64);
    q += __shfl_xor(q, sh, 64);
  }
  int w = threadIdx.x >> 6, l = threadIdx.x & 63;
  if (l == 0){ sred[w] = s; sred[4 + w] = c; sred[8 + w] = q; }
  __syncthreads();
  if (threadIdx.x == 0){
    spart[blockIdx.x * 3 + 0] = sred[0] + sred[1] + sred[2] + sred[3];
    spart[blockIdx.x * 3 + 1] = sred[4] + sred[5] + sred[6] + sred[7];
    spart[blockIdx.x * 3 + 2] = sred[8] + sred[9] + sred[10] + sred[11];
  }
}

// reduce 625 stat partials -> stats[0] = std/100
__global__ void k_stat2(const float* __restrict__ spart, float* __restrict__ stats){
  __shared__ float sred[12];
  int tid = threadIdx.x;
  float s = 0.f, c = 0.f, q = 0.f;
  for (int i = tid; i < 625; i += 256){
    s += spart[i * 3 + 0];
    c += spart[i * 3 + 1];
    q += spart[i * 3 + 2];
  }
#pragma unroll
  for (int sh = 32; sh >= 1; sh >>= 1){
    s += __shfl_xor(s, sh, 64);
    c += __shfl_xor(c, sh, 64);
    q += __shfl_xor(q, sh, 64);
  }
  int w = tid >> 6, l = tid & 63;
  if (l == 0){ sred[w] = s; sred[4 + w] = c; sred[8 + w] = q; }
  __syncthreads();
  if (tid == 0){
    float S = sred[0] + sred[1] + sred[2] + sred[3];
    float C = sred[4] + sred[5] + sred[6] + sred[7];
    float Q = sred[8] + sred[9] + sred[10] + sred[11];
    float var = (Q - S * S / C) / (C - 1.f);
    stats[0] = sqrtf(var) * 0.01f;
  }
}

__global__ void k_noise(const float* __restrict__ y, const float* __restrict__ stats,
                        float* __restrict__ x0){
  int n = blockIdx.x * 256 + threadIdx.x;
  float v = y[n];
  if (v != 0.0f){ x0[n] = v; return; }
  float scale = stats[0];
  unsigned bits = rbits(KN.a, KN.b, (unsigned)n);
  float f = __uint_as_float((bits >> 9) | 0x3f800000u) - 1.0f;
  float u = f * 2.0f + (-0.99999994f);
  u = fmaxf(-0.99999994f, u);
  float nrm = 1.41421356237f * erfinv_xla(u);
  x0[n] = scale * nrm;
}

// ---------------- fused GAT pass: LDS-staged x + online softmax (base-2 domain) ----------------
__global__ __launch_bounds__(256)
void k_gat(const float* __restrict__ xin, const float* __restrict__ xres,
           const int* __restrict__ offs, const unsigned short* __restrict__ srcs16,
           const float* __restrict__ gw, const float* __restrict__ asrc,
           const float* __restrict__ adst, const float* __restrict__ gbias,
           const float* __restrict__ bng, const float* __restrict__ bnb,
           const float* __restrict__ bnm, const float* __restrict__ bnv,
           float* __restrict__ xout){
  __shared__ float xsh[N_];                      // whole graph: 40 KB
  int g = blockIdx.x / GB_, c = blockIdx.x - g * GB_;
  int tid = threadIdx.x;
  const float4* xv = (const float4*)(xin + g * N_);
  for (int i = tid; i < N_ / 4; i += 256) ((float4*)xsh)[i] = xv[i];
  __syncthreads();
  if (tid >= GC_) return;

  int nl = c * GC_ + tid;
  int n = g * N_ + nl;
  float xn = xsh[nl];

  // coefficients pre-scaled by log2e: 2^(a*log2e) == e^a, softmax unchanged
  float cs[H_], cdxn[H_], wv[H_];
#pragma unroll
  for (int h = 0; h < H_; ++h){
    wv[h] = gw[h];
    cs[h] = wv[h] * asrc[h] * LOG2E_;
    cdxn[h] = wv[h] * adst[h] * xn * LOG2E_;
  }
  float mh[H_], den[H_], num[H_];
#pragma unroll
  for (int h = 0; h < H_; ++h){
    float v = cs[h] * xn + cdxn[h];
    v = (v > 0.f) ? v : 0.2f * v;
    mh[h] = v; den[h] = 1.f; num[h] = xn;
  }
  int e0 = offs[n], e1 = offs[n + 1];
  for (int e = e0; e < e1; ++e){
    float xs = xsh[srcs16[e]];
#pragma unroll
    for (int h = 0; h < H_; ++h){
      float v = fmaf(cs[h], xs, cdxn[h]);
      v = (v > 0.f) ? v : 0.2f * v;
      float nm = fmaxf(mh[h], v);
      float corr = exp2f(mh[h] - nm);
      float p = exp2f(v - nm);
      den[h] = fmaf(den[h], corr, p);
      num[h] = fmaf(num[h], corr, p * xs);
      mh[h] = nm;
    }
  }
  float o = 0.f;
#pragma unroll
  for (int h = 0; h < H_; ++h) o += wv[h] * num[h] / den[h];
  o = o * 0.125f + gbias[0];
  o = (o - bnm[0]) / sqrtf(bnv[0] + EPS_) * bng[0] + bnb[0];
  o = o / (1.0f + __expf(-o));
  xout[n] = o + xres[n];
}

// ---------------- final pool + linear + relu ----------------
__global__ __launch_bounds__(256)
void k_pool1(const float* __restrict__ xf, const float* __restrict__ dv,
             float* __restrict__ pmax){
  __shared__ float sred[4];
  int g = blockIdx.x / GB_, c = blockIdx.x - g * GB_;
  int tid = threadIdx.x;
  float m = -INFINITY;
  if (tid < GC_){
    int nl = c * GC_ + tid;
    m = xf[g * N_ + nl] * dv[nl];
  }
#pragma unroll
  for (int s = 32; s >= 1; s >>= 1) m = fmaxf(m, __shfl_xor(m, s, 64));
  int w = tid >> 6, l = tid & 63;
  if (l == 0) sred[w] = m;
  __syncthreads();
  if (tid == 0)
    pmax[blockIdx.x] = fmaxf(fmaxf(sred[0], sred[1]), fmaxf(sred[2], sred[3]));
}

__global__ void k_pool2(const float* __restrict__ pmax, const float* __restrict__ lw,
                        const float* __restrict__ lb, float* __restrict__ out){
  int b = blockIdx.x, l = threadIdx.x;
  float m = (l < GB_) ? pmax[b * GB_ + l] : -INFINITY;
#pragma unroll
  for (int s = 32; s >= 1; s >>= 1) m = fmaxf(m, __shfl_xor(m, s, 64));
  if (l == 0){
    float o = m * lw[0] + lb[0];
    out[b] = (o > 0.f) ? o : 0.f;
  }
}

// ---------------- launch ----------------
extern "C" void kernel_launch(void* const* d_in, const int* in_sizes, int n_in,
                              void* d_out, int out_size, void* d_ws, size_t ws_size,
                              hipStream_t stream){
  const float* x     = (const float*)d_in[0];
  const int*   ei    = (const int*)d_in[1];
  const float* W     = (const float*)d_in[3];
  const float* dv    = (const float*)d_in[4];
  const float* gw    = (const float*)d_in[5];
  const float* asrc  = (const float*)d_in[6];
  const float* adst  = (const float*)d_in[7];
  const float* gbias = (const float*)d_in[8];
  const float* bng   = (const float*)d_in[9];
  const float* bnb   = (const float*)d_in[10];
  const float* bnm   = (const float*)d_in[11];
  const float* bnv   = (const float*)d_in[12];
  const float* lw    = (const float*)d_in[13];
  const float* lb    = (const float*)d_in[14];
  float* out = (float*)d_out;

  char* ws = (char*)d_ws;
  int*            offs   = (int*)           (ws + 0);         // NT_+1 ints
  unsigned short* srcs16 = (unsigned short*)(ws + 640256);    // E_ u16 (10.24 MB)
  int*            cnt    = (int*)           (ws + 10880256);  // EB_*NB_ ints
  int*            gscan  = (int*)           (ws + 11520256);  // EB_*NB_ ints
  unsigned*       ebuf   = (unsigned*)      (ws + 21120256);  // E_ u32
  float*          ypart  = (float*)         (ws + 21120256);  // aliases ebuf (dead after bcsr)
  float*          y      = (float*)         (ws + 41600256);  // NT_ f32 (x_res)
  float*          x0     = (float*)         (ws + 42240256);  // NT_ f32
  float*          x1     = (float*)         (ws + 42880256);  // NT_ f32
  int*            bsum   = (int*)           (ws + 43520256);  // NB_ ints
  int*            boff   = (int*)           (ws + 43522816);  // NB_+1 ints
  float*          pmax   = (float*)         (ws + 43525376);  // B_*GB_ f32
  float*          stats  = (float*)         (ws + 43527936);  // 8 f32
  float*          spart  = (float*)         (ws + 43527968);  // 625*3 f32
  if (ws_size < (size_t)43535500) return;

  const int* esrc = ei;
  const int* edst = ei + E_;

  k_hist  <<<EB_, 256, 0, stream>>>(edst, cnt);
  k_sumb  <<<NB_, 256, 0, stream>>>(cnt, bsum);
  k_scanb <<<1, 256, 0, stream>>>(bsum, boff);
  k_scanc <<<NB_, 256, 0, stream>>>(cnt, boff, gscan);
  k_append<<<EB_, 256, 0, stream>>>(esrc, edst, gscan, ebuf);
  k_bcsr  <<<NB_, 256, 0, stream>>>(boff, ebuf, offs, srcs16);
  k_perm  <<<T_ * B_ * JC_, 512, 0, stream>>>(W, x, ypart);
  k_ycomb <<<625, 256, 0, stream>>>(ypart, y, spart);
  k_stat2 <<<1, 256, 0, stream>>>(spart, stats);
  k_noise <<<625, 256, 0, stream>>>(y, stats, x0);
  k_gat<<<B_ * GB_, 256, 0, stream>>>(x0, y, offs, srcs16, gw, asrc, adst, gbias, bng, bnb, bnm, bnv, x1);
  k_gat<<<B_ * GB_, 256, 0, stream>>>(x1, y, offs, srcs16, gw, asrc, adst, gbias, bng, bnb, bnm, bnv, x0);
  k_gat<<<B_ * GB_, 256, 0, stream>>>(x0, y, offs, srcs16, gw, asrc, adst, gbias, bng, bnb, bnm, bnv, x1);
  k_gat<<<B_ * GB_, 256, 0, stream>>>(x1, y, offs, srcs16, gw, asrc, adst, gbias, bng, bnb, bnm, bnv, x0);
  k_pool1 <<<B_ * GB_, 256, 0, stream>>>(x0, dv, pmax);
  k_pool2 <<<B_, 64, 0, stream>>>(pmax, lw, lb, out);
}

// Round 7
// 360.574 us; speedup vs baseline: 1.3294x; 1.3294x over previous
//
#include <hip/hip_runtime.h>
#include <stdint.h>
#include <math.h>

#define B_   16
#define T_   50
#define C_   200
#define N_   10000      // T_*C_
#define NT_  160000     // B_*N_
#define H_   8
#define E_   5120000
#define EPS_ 1e-5f
#define NB_  625        // CSR buckets: dst>>8
#define EB_  256        // edge blocks for hist/append
#define EPB_ 20000      // edges per block (E_/EB_)
#define GB_  40         // chunks per graph (gat/pool)
#define GC_  250        // nodes per chunk (N_/GB_)
#define JC_  5          // column chunks per perm tile
#define JW_  40         // columns per chunk
#define ROWP_ 41        // padded LDS row stride (2-way max on 32 banks = free)
#define LOG2E_ 1.44269504088896340736f

// native v_exp_f32: D = 2^S0 (single instruction)
__device__ __forceinline__ float ex2(float x){
  float r; asm("v_exp_f32 %0, %1" : "=v"(r) : "v"(x)); return r;
}

// ---------------- Threefry-2x32 (JAX) ----------------
struct TF2C { unsigned a, b; };
constexpr unsigned rotl32c(unsigned v, int r){ return (v << r) | (v >> (32 - r)); }
constexpr TF2C tf_const(unsigned k0, unsigned k1, unsigned x0, unsigned x1){
  unsigned ks2 = k0 ^ k1 ^ 0x1BD11BDAu;
  unsigned ks[3] = {k0, k1, ks2};
  x0 += k0; x1 += k1;
  const int RA[4] = {13, 15, 26, 6};
  const int RB[4] = {17, 29, 16, 24};
  for (int g = 0; g < 5; ++g){
    for (int r = 0; r < 4; ++r){
      int rr = (g & 1) ? RB[r] : RA[r];
      x0 += x1; x1 = rotl32c(x1, rr); x1 ^= x0;
    }
    x0 += ks[(g + 1) % 3];
    x1 += ks[(g + 2) % 3] + (unsigned)(g + 1);
  }
  return TF2C{x0, x1};
}
constexpr TF2C KG = tf_const(0u, 42u, 0u, 0u);
constexpr TF2C KN = tf_const(0u, 42u, 0u, 1u);

__device__ __forceinline__ void tf2(unsigned k0, unsigned k1, unsigned x0, unsigned x1,
                                    unsigned &o0, unsigned &o1){
  unsigned ks2 = k0 ^ k1 ^ 0x1BD11BDAu;
  x0 += k0; x1 += k1;
#define TFR_(R) { x0 += x1; x1 = __builtin_rotateleft32(x1, R); x1 ^= x0; }
  TFR_(13) TFR_(15) TFR_(26) TFR_(6)  x0 += k1;  x1 += ks2 + 1u;
  TFR_(17) TFR_(29) TFR_(16) TFR_(24) x0 += ks2; x1 += k0 + 2u;
  TFR_(13) TFR_(15) TFR_(26) TFR_(6)  x0 += k0;  x1 += k1 + 3u;
  TFR_(17) TFR_(29) TFR_(16) TFR_(24) x0 += k1;  x1 += ks2 + 4u;
  TFR_(13) TFR_(15) TFR_(26) TFR_(6)  x0 += ks2; x1 += k0 + 5u;
#undef TFR_
  o0 = x0; o1 = x1;
}
__device__ __forceinline__ unsigned rbits(unsigned ka, unsigned kb, unsigned m){
  unsigned a, b; tf2(ka, kb, 0u, m, a, b); return a ^ b;
}

__device__ __forceinline__ float erfinv_xla(float x){
  float w = -log1pf(-x * x);
  float p;
  if (w < 5.0f){
    w = w - 2.5f;
    p = 2.81022636e-08f;
    p = fmaf(p, w, 3.43273939e-07f);
    p = fmaf(p, w, -3.5233877e-06f);
    p = fmaf(p, w, -4.39150654e-06f);
    p = fmaf(p, w, 0.00021858087f);
    p = fmaf(p, w, -0.00125372503f);
    p = fmaf(p, w, -0.00417768164f);
    p = fmaf(p, w, 0.246640727f);
    p = fmaf(p, w, 1.50140941f);
  } else {
    w = sqrtf(w) - 3.0f;
    p = -0.000200214257f;
    p = fmaf(p, w, 0.000100950558f);
    p = fmaf(p, w, 0.00134934322f);
    p = fmaf(p, w, -0.00367342844f);
    p = fmaf(p, w, 0.00573950773f);
    p = fmaf(p, w, -0.0076224613f);
    p = fmaf(p, w, 0.00943887047f);
    p = fmaf(p, w, 1.00167406f);
    p = fmaf(p, w, 2.83297682f);
  }
  return p * x;
}

// ---------------- CSR build: atomic-free placement ----------------
__global__ __launch_bounds__(256)
void k_hist(const int* __restrict__ dst, int* __restrict__ cnt){
  __shared__ int h[NB_];
  int tid = threadIdx.x, blk = blockIdx.x;
  for (int i = tid; i < NB_; i += 256) h[i] = 0;
  __syncthreads();
  int e0 = blk * EPB_;
  for (int i = tid; i < EPB_; i += 256)
    atomicAdd(&h[dst[e0 + i] >> 8], 1);
  __syncthreads();
  for (int i = tid; i < NB_; i += 256) cnt[blk * NB_ + i] = h[i];
}

__global__ __launch_bounds__(256)
void k_sumb(const int* __restrict__ cnt, int* __restrict__ bsum){
  __shared__ int sred[4];
  int b = blockIdx.x, tid = threadIdx.x;
  int v = cnt[tid * NB_ + b];
#pragma unroll
  for (int s = 32; s >= 1; s >>= 1) v += __shfl_xor(v, s, 64);
  int w = tid >> 6, l = tid & 63;
  if (l == 0) sred[w] = v;
  __syncthreads();
  if (tid == 0) bsum[b] = sred[0] + sred[1] + sred[2] + sred[3];
}

__global__ void k_scanb(const int* __restrict__ bsum, int* __restrict__ boff){
  __shared__ int ts[256];
  int tid = threadIdx.x;
  int i0 = tid * 3;
  int c0 = (i0 + 0 < NB_) ? bsum[i0 + 0] : 0;
  int c1 = (i0 + 1 < NB_) ? bsum[i0 + 1] : 0;
  int c2 = (i0 + 2 < NB_) ? bsum[i0 + 2] : 0;
  int s = c0 + c1 + c2;
  ts[tid] = s;
  __syncthreads();
  for (int d = 1; d < 256; d <<= 1){
    int t = (tid >= d) ? ts[tid - d] : 0;
    __syncthreads();
    ts[tid] += t;
    __syncthreads();
  }
  int run = ts[tid] - s;
  if (i0 + 0 <= NB_){ boff[i0 + 0] = run; run += c0; }
  if (i0 + 1 <= NB_){ boff[i0 + 1] = run; run += c1; }
  if (i0 + 2 <= NB_){ boff[i0 + 2] = run; run += c2; }
}

__global__ __launch_bounds__(256)
void k_scanc(const int* __restrict__ cnt, const int* __restrict__ boff,
             int* __restrict__ gscan){
  __shared__ int ts[256];
  int b = blockIdx.x, tid = threadIdx.x;
  int v = cnt[tid * NB_ + b];
  ts[tid] = v;
  __syncthreads();
  for (int d = 1; d < 256; d <<= 1){
    int t = (tid >= d) ? ts[tid - d] : 0;
    __syncthreads();
    ts[tid] += t;
    __syncthreads();
  }
  gscan[tid * NB_ + b] = boff[b] + ts[tid] - v;
}

__global__ __launch_bounds__(256)
void k_append(const int* __restrict__ src, const int* __restrict__ dst,
              const int* __restrict__ gscan, unsigned* __restrict__ ebuf){
  __shared__ int gb[NB_];
  __shared__ int lc[NB_];
  int tid = threadIdx.x, blk = blockIdx.x;
  for (int i = tid; i < NB_; i += 256){ gb[i] = gscan[blk * NB_ + i]; lc[i] = 0; }
  __syncthreads();
  int e0 = blk * EPB_;
  for (int i = tid; i < EPB_; i += 256){
    int e = e0 + i;
    int d = dst[e];
    int b = d >> 8;
    int r = atomicAdd(&lc[b], 1);
    ebuf[gb[b] + r] = ((unsigned)src[e] << 8) | (unsigned)(d & 255);
  }
}

// one workgroup per bucket: exact per-node offsets + in-bucket scatter (u16 local src)
__global__ __launch_bounds__(256)
void k_bcsr(const int* __restrict__ boff, const unsigned* __restrict__ ebuf,
            int* __restrict__ offs, unsigned short* __restrict__ srcs16){
  __shared__ int cnt[256];
  __shared__ int ts[256];
  int b = blockIdx.x, tid = threadIdx.x;
  int e0 = boff[b], e1 = boff[b + 1];
  int base_node = b * 256;
  int offA = (base_node / N_) * N_;          // graph base of first node in bucket
  int boundary = offA + N_;                  // bucket straddles at most one boundary
  cnt[tid] = 0;
  __syncthreads();
  for (int e = e0 + tid; e < e1; e += 256)
    atomicAdd(&cnt[ebuf[e] & 255u], 1);
  __syncthreads();
  int v = cnt[tid];
  ts[tid] = v;
  __syncthreads();
  for (int d = 1; d < 256; d <<= 1){
    int t = (tid >= d) ? ts[tid - d] : 0;
    __syncthreads();
    ts[tid] += t;
    __syncthreads();
  }
  int excl = ts[tid] - v;
  offs[base_node + tid] = e0 + excl;
  __syncthreads();
  cnt[tid] = excl;
  __syncthreads();
  for (int e = e0 + tid; e < e1; e += 256){
    unsigned pk = ebuf[e];
    int dl = (int)(pk & 255u);
    int goff = (base_node + dl >= boundary) ? boundary : offA;
    int pos = e0 + atomicAdd(&cnt[dl], 1);
    srcs16[pos] = (unsigned short)((int)(pk >> 8) - goff);
  }
  if (b == 0 && tid == 0) offs[NT_] = E_;
}

// ---------------- permutation layer ----------------
// ez = exp(W + gumbel) = exp(W) / t, t = -log(u).  Incremental addressing, no div.
__global__ __launch_bounds__(512, 8)
void k_perm(const float* __restrict__ W, const float* __restrict__ x,
            float* __restrict__ ypart){
  __shared__ float ez[C_ * ROWP_];          // 32.8 KB
  __shared__ float Ssh[JW_];
  __shared__ float rs[JW_];

  const int bid = blockIdx.x;               // tb*JC_ + jc
  const int tb = bid / JC_;
  const int jc = bid - tb * JC_;
  const int t = tb / B_;
  const int b = tb - t * B_;
  const int j0 = jc * JW_;
  const int xoff = (b * T_ + t) * C_;
  const int tid = threadIdx.x;
  const int w = tid >> 6, l = tid & 63;

  // stage ez = exp(W)/(-log(u)); e walks tid, tid+512, ... over C_*JW_ elements
  {
    int i = tid / JW_;
    int jj = tid - i * JW_;
    unsigned m = (unsigned)(tb * (C_ * C_) + i * C_ + j0 + jj);  // W idx AND rng ctr
    int la = i * ROWP_ + jj;
    int niter = (C_ * JW_ - tid + 511) >> 9;
    for (int it = 0; it < niter; ++it){
      unsigned bits = rbits(KG.a, KG.b, m);
      float f = __uint_as_float((bits >> 9) | 0x3f800000u) - 1.0f;   // [0,1) exact
      float tneg;
      if (f >= 0.875f){
        float d = 1.0f - f;                  // exact (Sterbenz)
        float p = 0.16666667f;               // -log(1-d) = d*(1+d/2+...+d^5/6)
        p = fmaf(p, d, 0.2f);
        p = fmaf(p, d, 0.25f);
        p = fmaf(p, d, 0.33333333f);
        p = fmaf(p, d, 0.5f);
        p = fmaf(p, d, 1.0f);
        tneg = d * p;
      } else {
        float u = f + 1e-10f;                // uniform(1e-10,1); f>=0 so >= 1e-10
        tneg = -__logf(u);
      }
      ez[la] = __expf(W[m]) * __builtin_amdgcn_rcpf(tneg);
      // advance by 512 elements: Δ(i,jj) = (12,+32) or (13,-8)
      jj += 32;
      int wrap = jj >= JW_;
      jj = wrap ? jj - JW_ : jj;
      m += wrap ? 2592u : 2432u;             // Δi*C_ + Δjj
      la += wrap ? 525 : 524;                // Δi*ROWP_ + Δjj
    }
  }
  __syncthreads();

  // column sums (over rows i), 5 columns per wave (8 waves)
#pragma unroll
  for (int q = 0; q < 5; ++q){
    int jj = w * 5 + q;
    float s = ez[l * ROWP_ + jj] + ez[(l + 64) * ROWP_ + jj] + ez[(l + 128) * ROWP_ + jj]
            + ((l < 8) ? ez[(l + 192) * ROWP_ + jj] : 0.f);
#pragma unroll
    for (int sh = 32; sh >= 1; sh >>= 1) s += __shfl_xor(s, sh, 64);
    if (l == 0) Ssh[jj] = s;
  }
  __syncthreads();
  if (tid < JW_) rs[tid] = x[xoff + j0 + tid] / Ssh[tid];
  __syncthreads();

  // per-row partial y
  if (tid < C_){
    float acc = 0.f;
#pragma unroll 8
    for (int jj = 0; jj < JW_; ++jj)
      acc = fmaf(ez[tid * ROWP_ + jj], rs[jj], acc);
    ypart[jc * NT_ + xoff + tid] = acc;
  }
}

// combine 5 column-chunk partials -> y, plus nonzero stats partials
__global__ __launch_bounds__(256)
void k_ycomb(const float* __restrict__ ypart, float* __restrict__ y,
             float* __restrict__ spart){
  __shared__ float sred[12];
  int n = blockIdx.x * 256 + threadIdx.x;
  float v = 0.f;
#pragma unroll
  for (int jc = 0; jc < JC_; ++jc) v += ypart[jc * NT_ + n];
  y[n] = v;
  float s = 0.f, c = 0.f, q = 0.f;
  if (v != 0.f){ s = v; c = 1.f; q = v * v; }
#pragma unroll
  for (int sh = 32; sh >= 1; sh >>= 1){
    s += __shfl_xor(s, sh, 64);
    c += __shfl_xor(c, sh, 64);
    q += __shfl_xor(q, sh, 64);
  }
  int w = threadIdx.x >> 6, l = threadIdx.x & 63;
  if (l == 0){ sred[w] = s; sred[4 + w] = c; sred[8 + w] = q; }
  __syncthreads();
  if (threadIdx.x == 0){
    spart[blockIdx.x * 3 + 0] = sred[0] + sred[1] + sred[2] + sred[3];
    spart[blockIdx.x * 3 + 1] = sred[4] + sred[5] + sred[6] + sred[7];
    spart[blockIdx.x * 3 + 2] = sred[8] + sred[9] + sred[10] + sred[11];
  }
}

// reduce 625 stat partials -> stats[0] = std/100
__global__ void k_stat2(const float* __restrict__ spart, float* __restrict__ stats){
  __shared__ float sred[12];
  int tid = threadIdx.x;
  float s = 0.f, c = 0.f, q = 0.f;
  for (int i = tid; i < 625; i += 256){
    s += spart[i * 3 + 0];
    c += spart[i * 3 + 1];
    q += spart[i * 3 + 2];
  }
#pragma unroll
  for (int sh = 32; sh >= 1; sh >>= 1){
    s += __shfl_xor(s, sh, 64);
    c += __shfl_xor(c, sh, 64);
    q += __shfl_xor(q, sh, 64);
  }
  int w = tid >> 6, l = tid & 63;
  if (l == 0){ sred[w] = s; sred[4 + w] = c; sred[8 + w] = q; }
  __syncthreads();
  if (tid == 0){
    float S = sred[0] + sred[1] + sred[2] + sred[3];
    float C = sred[4] + sred[5] + sred[6] + sred[7];
    float Q = sred[8] + sred[9] + sred[10] + sred[11];
    float var = (Q - S * S / C) / (C - 1.f);
    stats[0] = sqrtf(var) * 0.01f;
  }
}

__global__ void k_noise(const float* __restrict__ y, const float* __restrict__ stats,
                        float* __restrict__ x0){
  int n = blockIdx.x * 256 + threadIdx.x;
  float v = y[n];
  if (v != 0.0f){ x0[n] = v; return; }
  float scale = stats[0];
  unsigned bits = rbits(KN.a, KN.b, (unsigned)n);
  float f = __uint_as_float((bits >> 9) | 0x3f800000u) - 1.0f;
  float u = f * 2.0f + (-0.99999994f);
  u = fmaxf(-0.99999994f, u);
  float nrm = 1.41421356237f * erfinv_xla(u);
  x0[n] = scale * nrm;
}

// ---------------- fused GAT pass: LDS x, online softmax, 1 native exp/edge-head ----------------
__global__ __launch_bounds__(256)
void k_gat(const float* __restrict__ xin, const float* __restrict__ xres,
           const int* __restrict__ offs, const unsigned short* __restrict__ srcs16,
           const float* __restrict__ gw, const float* __restrict__ asrc,
           const float* __restrict__ adst, const float* __restrict__ gbias,
           const float* __restrict__ bng, const float* __restrict__ bnb,
           const float* __restrict__ bnm, const float* __restrict__ bnv,
           float* __restrict__ xout){
  __shared__ float xsh[N_];                      // whole graph: 40 KB
  int g = blockIdx.x / GB_, c = blockIdx.x - g * GB_;
  int tid = threadIdx.x;
  const float4* xv = (const float4*)(xin + g * N_);
  for (int i = tid; i < N_ / 4; i += 256) ((float4*)xsh)[i] = xv[i];
  __syncthreads();
  if (tid >= GC_) return;

  int nl = c * GC_ + tid;
  int n = g * N_ + nl;
  float xn = xsh[nl];

  // coefficients pre-scaled by log2e: 2^(a*log2e) == e^a
  float cs[H_], cdxn[H_], wv[H_];
#pragma unroll
  for (int h = 0; h < H_; ++h){
    wv[h] = gw[h];
    cs[h] = wv[h] * asrc[h] * LOG2E_;
    cdxn[h] = wv[h] * adst[h] * xn * LOG2E_;
  }
  float mh[H_], den[H_], num[H_];
#pragma unroll
  for (int h = 0; h < H_; ++h){
    float v = cs[h] * xn + cdxn[h];
    v = fmaxf(v, 0.2f * v);                 // leaky relu
    mh[h] = v; den[h] = 1.f; num[h] = xn;
  }
  int e0 = offs[n], e1 = offs[n + 1];
  for (int e = e0; e < e1; ++e){
    float xs = xsh[srcs16[e]];
#pragma unroll
    for (int h = 0; h < H_; ++h){
      float v = fmaf(cs[h], xs, cdxn[h]);
      v = fmaxf(v, 0.2f * v);
      float d = v - mh[h];
      float ed = ex2(-fabsf(d));            // exp2(-|d|): the non-unit factor
      bool newmax = d > 0.f;
      float corr = newmax ? ed : 1.f;       // one of corr,p is exactly 1
      float p    = newmax ? 1.f : ed;
      mh[h] = newmax ? v : mh[h];
      den[h] = fmaf(den[h], corr, p);
      num[h] = fmaf(num[h], corr, p * xs);
    }
  }
  float o = 0.f;
#pragma unroll
  for (int h = 0; h < H_; ++h) o += wv[h] * num[h] * __builtin_amdgcn_rcpf(den[h]);
  o = o * 0.125f + gbias[0];
  o = (o - bnm[0]) / sqrtf(bnv[0] + EPS_) * bng[0] + bnb[0];
  o = o / (1.0f + __expf(-o));              // silu
  xout[n] = o + xres[n];
}

// ---------------- final pool + linear + relu ----------------
__global__ __launch_bounds__(256)
void k_pool1(const float* __restrict__ xf, const float* __restrict__ dv,
             float* __restrict__ pmax){
  __shared__ float sred[4];
  int g = blockIdx.x / GB_, c = blockIdx.x - g * GB_;
  int tid = threadIdx.x;
  float m = -INFINITY;
  if (tid < GC_){
    int nl = c * GC_ + tid;
    m = xf[g * N_ + nl] * dv[nl];
  }
#pragma unroll
  for (int s = 32; s >= 1; s >>= 1) m = fmaxf(m, __shfl_xor(m, s, 64));
  int w = tid >> 6, l = tid & 63;
  if (l == 0) sred[w] = m;
  __syncthreads();
  if (tid == 0)
    pmax[blockIdx.x] = fmaxf(fmaxf(sred[0], sred[1]), fmaxf(sred[2], sred[3]));
}

__global__ void k_pool2(const float* __restrict__ pmax, const float* __restrict__ lw,
                        const float* __restrict__ lb, float* __restrict__ out){
  int b = blockIdx.x, l = threadIdx.x;
  float m = (l < GB_) ? pmax[b * GB_ + l] : -INFINITY;
#pragma unroll
  for (int s = 32; s >= 1; s >>= 1) m = fmaxf(m, __shfl_xor(m, s, 64));
  if (l == 0){
    float o = m * lw[0] + lb[0];
    out[b] = (o > 0.f) ? o : 0.f;
  }
}

// ---------------- launch ----------------
extern "C" void kernel_launch(void* const* d_in, const int* in_sizes, int n_in,
                              void* d_out, int out_size, void* d_ws, size_t ws_size,
                              hipStream_t stream){
  const float* x     = (const float*)d_in[0];
  const int*   ei    = (const int*)d_in[1];
  const float* W     = (const float*)d_in[3];
  const float* dv    = (const float*)d_in[4];
  const float* gw    = (const float*)d_in[5];
  const float* asrc  = (const float*)d_in[6];
  const float* adst  = (const float*)d_in[7];
  const float* gbias = (const float*)d_in[8];
  const float* bng   = (const float*)d_in[9];
  const float* bnb   = (const float*)d_in[10];
  const float* bnm   = (const float*)d_in[11];
  const float* bnv   = (const float*)d_in[12];
  const float* lw    = (const float*)d_in[13];
  const float* lb    = (const float*)d_in[14];
  float* out = (float*)d_out;

  char* ws = (char*)d_ws;
  int*            offs   = (int*)           (ws + 0);         // NT_+1 ints
  unsigned short* srcs16 = (unsigned short*)(ws + 640256);    // E_ u16 (10.24 MB)
  int*            cnt    = (int*)           (ws + 10880256);  // EB_*NB_ ints
  int*            gscan  = (int*)           (ws + 11520256);  // EB_*NB_ ints
  unsigned*       ebuf   = (unsigned*)      (ws + 21120256);  // E_ u32
  float*          ypart  = (float*)         (ws + 21120256);  // aliases ebuf (dead after bcsr)
  float*          y      = (float*)         (ws + 41600256);  // NT_ f32 (x_res)
  float*          x0     = (float*)         (ws + 42240256);  // NT_ f32
  float*          x1     = (float*)         (ws + 42880256);  // NT_ f32
  int*            bsum   = (int*)           (ws + 43520256);  // NB_ ints
  int*            boff   = (int*)           (ws + 43522816);  // NB_+1 ints
  float*          pmax   = (float*)         (ws + 43525376);  // B_*GB_ f32
  float*          stats  = (float*)         (ws + 43527936);  // 8 f32
  float*          spart  = (float*)         (ws + 43527968);  // 625*3 f32
  if (ws_size < (size_t)43535500) return;

  const int* esrc = ei;
  const int* edst = ei + E_;

  k_hist  <<<EB_, 256, 0, stream>>>(edst, cnt);
  k_sumb  <<<NB_, 256, 0, stream>>>(cnt, bsum);
  k_scanb <<<1, 256, 0, stream>>>(bsum, boff);
  k_scanc <<<NB_, 256, 0, stream>>>(cnt, boff, gscan);
  k_append<<<EB_, 256, 0, stream>>>(esrc, edst, gscan, ebuf);
  k_bcsr  <<<NB_, 256, 0, stream>>>(boff, ebuf, offs, srcs16);
  k_perm  <<<T_ * B_ * JC_, 512, 0, stream>>>(W, x, ypart);
  k_ycomb <<<625, 256, 0, stream>>>(ypart, y, spart);
  k_stat2 <<<1, 256, 0, stream>>>(spart, stats);
  k_noise <<<625, 256, 0, stream>>>(y, stats, x0);
  k_gat<<<B_ * GB_, 256, 0, stream>>>(x0, y, offs, srcs16, gw, asrc, adst, gbias, bng, bnb, bnm, bnv, x1);
  k_gat<<<B_ * GB_, 256, 0, stream>>>(x1, y, offs, srcs16, gw, asrc, adst, gbias, bng, bnb, bnm, bnv, x0);
  k_gat<<<B_ * GB_, 256, 0, stream>>>(x0, y, offs, srcs16, gw, asrc, adst, gbias, bng, bnb, bnm, bnv, x1);
  k_gat<<<B_ * GB_, 256, 0, stream>>>(x1, y, offs, srcs16, gw, asrc, adst, gbias, bng, bnb, bnm, bnv, x0);
  k_pool1 <<<B_ * GB_, 256, 0, stream>>>(x0, dv, pmax);
  k_pool2 <<<B_, 64, 0, stream>>>(pmax, lw, lb, out);
}

// Round 8
// 325.874 us; speedup vs baseline: 1.4710x; 1.1065x over previous
//
#include <hip/hip_runtime.h>
#include <stdint.h>
#include <math.h>

#define B_   16
#define T_   50
#define C_   200
#define N_   10000      // T_*C_
#define NT_  160000     // B_*N_
#define H_   8
#define E_   5120000
#define EPS_ 1e-5f
#define NB_  625        // CSR buckets: dst>>8
#define EB_  512        // edge blocks for hist/append
#define EPB_ 10000      // edges per block (E_/EB_)
#define ATH_ 1024       // threads for hist/append
#define GB_  40         // chunks per graph (gat/pool)
#define GC_  250        // nodes per chunk (N_/GB_)
#define JC_  5          // column chunks per perm tile
#define JW_  40         // columns per chunk
#define ROWP_ 41        // padded LDS row stride (2-way max on 32 banks = free)
#define LOG2E_ 1.44269504088896340736f

// native v_exp_f32: D = 2^S0 (single instruction)
__device__ __forceinline__ float ex2(float x){
  float r; asm("v_exp_f32 %0, %1" : "=v"(r) : "v"(x)); return r;
}

// ---------------- Threefry-2x32 (JAX) ----------------
struct TF2C { unsigned a, b; };
constexpr unsigned rotl32c(unsigned v, int r){ return (v << r) | (v >> (32 - r)); }
constexpr TF2C tf_const(unsigned k0, unsigned k1, unsigned x0, unsigned x1){
  unsigned ks2 = k0 ^ k1 ^ 0x1BD11BDAu;
  unsigned ks[3] = {k0, k1, ks2};
  x0 += k0; x1 += k1;
  const int RA[4] = {13, 15, 26, 6};
  const int RB[4] = {17, 29, 16, 24};
  for (int g = 0; g < 5; ++g){
    for (int r = 0; r < 4; ++r){
      int rr = (g & 1) ? RB[r] : RA[r];
      x0 += x1; x1 = rotl32c(x1, rr); x1 ^= x0;
    }
    x0 += ks[(g + 1) % 3];
    x1 += ks[(g + 2) % 3] + (unsigned)(g + 1);
  }
  return TF2C{x0, x1};
}
constexpr TF2C KG = tf_const(0u, 42u, 0u, 0u);
constexpr TF2C KN = tf_const(0u, 42u, 0u, 1u);

__device__ __forceinline__ void tf2(unsigned k0, unsigned k1, unsigned x0, unsigned x1,
                                    unsigned &o0, unsigned &o1){
  unsigned ks2 = k0 ^ k1 ^ 0x1BD11BDAu;
  x0 += k0; x1 += k1;
#define TFR_(R) { x0 += x1; x1 = __builtin_rotateleft32(x1, R); x1 ^= x0; }
  TFR_(13) TFR_(15) TFR_(26) TFR_(6)  x0 += k1;  x1 += ks2 + 1u;
  TFR_(17) TFR_(29) TFR_(16) TFR_(24) x0 += ks2; x1 += k0 + 2u;
  TFR_(13) TFR_(15) TFR_(26) TFR_(6)  x0 += k0;  x1 += k1 + 3u;
  TFR_(17) TFR_(29) TFR_(16) TFR_(24) x0 += k1;  x1 += ks2 + 4u;
  TFR_(13) TFR_(15) TFR_(26) TFR_(6)  x0 += ks2; x1 += k0 + 5u;
#undef TFR_
  o0 = x0; o1 = x1;
}
__device__ __forceinline__ unsigned rbits(unsigned ka, unsigned kb, unsigned m){
  unsigned a, b; tf2(ka, kb, 0u, m, a, b); return a ^ b;
}

__device__ __forceinline__ float erfinv_xla(float x){
  float w = -log1pf(-x * x);
  float p;
  if (w < 5.0f){
    w = w - 2.5f;
    p = 2.81022636e-08f;
    p = fmaf(p, w, 3.43273939e-07f);
    p = fmaf(p, w, -3.5233877e-06f);
    p = fmaf(p, w, -4.39150654e-06f);
    p = fmaf(p, w, 0.00021858087f);
    p = fmaf(p, w, -0.00125372503f);
    p = fmaf(p, w, -0.00417768164f);
    p = fmaf(p, w, 0.246640727f);
    p = fmaf(p, w, 1.50140941f);
  } else {
    w = sqrtf(w) - 3.0f;
    p = -0.000200214257f;
    p = fmaf(p, w, 0.000100950558f);
    p = fmaf(p, w, 0.00134934322f);
    p = fmaf(p, w, -0.00367342844f);
    p = fmaf(p, w, 0.00573950773f);
    p = fmaf(p, w, -0.0076224613f);
    p = fmaf(p, w, 0.00943887047f);
    p = fmaf(p, w, 1.00167406f);
    p = fmaf(p, w, 2.83297682f);
  }
  return p * x;
}

// ---------------- CSR build: atomic-free placement, LDS-sorted append ----------------
__global__ __launch_bounds__(ATH_)
void k_hist(const int* __restrict__ dst, int* __restrict__ cnt){
  __shared__ int h[NB_];
  int tid = threadIdx.x, blk = blockIdx.x;
  for (int i = tid; i < NB_; i += ATH_) h[i] = 0;
  __syncthreads();
  int e0 = blk * EPB_;
  for (int i = tid; i < EPB_; i += ATH_)
    atomicAdd(&h[dst[e0 + i] >> 8], 1);
  __syncthreads();
  for (int i = tid; i < NB_; i += ATH_) cnt[blk * NB_ + i] = h[i];
}

// bucket totals: bsum[b] = sum over blk of cnt[blk][b]   (EB_ = 512 blocks)
__global__ __launch_bounds__(512)
void k_sumb(const int* __restrict__ cnt, int* __restrict__ bsum){
  __shared__ int sred[8];
  int b = blockIdx.x, tid = threadIdx.x;
  int v = cnt[tid * NB_ + b];
#pragma unroll
  for (int s = 32; s >= 1; s >>= 1) v += __shfl_xor(v, s, 64);
  int w = tid >> 6, l = tid & 63;
  if (l == 0) sred[w] = v;
  __syncthreads();
  if (tid == 0){
    int t = 0;
#pragma unroll
    for (int i = 0; i < 8; ++i) t += sred[i];
    bsum[b] = t;
  }
}

__global__ void k_scanb(const int* __restrict__ bsum, int* __restrict__ boff){
  __shared__ int ts[256];
  int tid = threadIdx.x;
  int i0 = tid * 3;
  int c0 = (i0 + 0 < NB_) ? bsum[i0 + 0] : 0;
  int c1 = (i0 + 1 < NB_) ? bsum[i0 + 1] : 0;
  int c2 = (i0 + 2 < NB_) ? bsum[i0 + 2] : 0;
  int s = c0 + c1 + c2;
  ts[tid] = s;
  __syncthreads();
  for (int d = 1; d < 256; d <<= 1){
    int t = (tid >= d) ? ts[tid - d] : 0;
    __syncthreads();
    ts[tid] += t;
    __syncthreads();
  }
  int run = ts[tid] - s;
  if (i0 + 0 <= NB_){ boff[i0 + 0] = run; run += c0; }
  if (i0 + 1 <= NB_){ boff[i0 + 1] = run; run += c1; }
  if (i0 + 2 <= NB_){ boff[i0 + 2] = run; run += c2; }
}

// per-bucket exclusive scan over EB_ blocks -> gscan[blk*NB_+b] = region base
__global__ __launch_bounds__(512)
void k_scanc(const int* __restrict__ cnt, const int* __restrict__ boff,
             int* __restrict__ gscan){
  __shared__ int ts[512];
  int b = blockIdx.x, tid = threadIdx.x;
  int v = cnt[tid * NB_ + b];
  ts[tid] = v;
  __syncthreads();
  for (int d = 1; d < 512; d <<= 1){
    int t = (tid >= d) ? ts[tid - d] : 0;
    __syncthreads();
    ts[tid] += t;
    __syncthreads();
  }
  gscan[tid * NB_ + b] = boff[b] + ts[tid] - v;
}

// LDS counting sort per block, then contiguous burst flush per bucket-run
__global__ __launch_bounds__(ATH_)
void k_append(const int* __restrict__ src, const int* __restrict__ dst,
              const int* __restrict__ gscan, unsigned* __restrict__ ebuf){
  __shared__ unsigned esh[EPB_];     // 40 KB staging
  __shared__ int hist[NB_];          // counts, then cursors
  __shared__ int loff[NB_ + 1];      // local exclusive offsets
  int tid = threadIdx.x, blk = blockIdx.x;
  int e0 = blk * EPB_;
  for (int i = tid; i < NB_; i += ATH_) hist[i] = 0;
  __syncthreads();
  // pass 1: local histogram
  for (int i = tid; i < EPB_; i += ATH_)
    atomicAdd(&hist[dst[e0 + i] >> 8], 1);
  __syncthreads();
  // LDS scan (Hillis-Steele, 625 <= 1024: one slot per thread)
  if (tid < NB_) loff[tid + 1] = hist[tid];
  if (tid == 0) loff[0] = 0;
  __syncthreads();
  for (int d = 1; d < NB_; d <<= 1){
    int v = 0;
    if (tid < NB_ && tid >= d) v = loff[tid + 1 - d];
    __syncthreads();
    if (tid < NB_ && tid >= d) loff[tid + 1] += v;
    __syncthreads();
  }
  for (int i = tid; i < NB_; i += ATH_) hist[i] = 0;   // reuse as cursor
  __syncthreads();
  // pass 2: place packed entries into LDS
  for (int i = tid; i < EPB_; i += ATH_){
    int e = e0 + i;
    int d = dst[e];
    int b = d >> 8;
    int p = loff[b] + atomicAdd(&hist[b], 1);
    esh[p] = ((unsigned)src[e] << 8) | (unsigned)(d & 255);
  }
  __syncthreads();
  // flush: each wave copies whole bucket-runs as contiguous bursts
  int wv = tid >> 6, ln = tid & 63;                    // 16 waves
  for (int b = wv; b < NB_; b += ATH_ / 64){
    int lo = loff[b], len = loff[b + 1] - lo;
    int gb0 = gscan[blk * NB_ + b];
    for (int p = ln; p < len; p += 64)
      ebuf[gb0 + p] = esh[lo + p];
  }
}

// one workgroup per bucket: exact per-node offsets + in-bucket scatter (u16 local src)
__global__ __launch_bounds__(256)
void k_bcsr(const int* __restrict__ boff, const unsigned* __restrict__ ebuf,
            int* __restrict__ offs, unsigned short* __restrict__ srcs16){
  __shared__ int cnt[256];
  __shared__ int ts[256];
  int b = blockIdx.x, tid = threadIdx.x;
  int e0 = boff[b], e1 = boff[b + 1];
  int base_node = b * 256;
  int offA = (base_node / N_) * N_;
  int boundary = offA + N_;
  cnt[tid] = 0;
  __syncthreads();
  for (int e = e0 + tid; e < e1; e += 256)
    atomicAdd(&cnt[ebuf[e] & 255u], 1);
  __syncthreads();
  int v = cnt[tid];
  ts[tid] = v;
  __syncthreads();
  for (int d = 1; d < 256; d <<= 1){
    int t = (tid >= d) ? ts[tid - d] : 0;
    __syncthreads();
    ts[tid] += t;
    __syncthreads();
  }
  int excl = ts[tid] - v;
  offs[base_node + tid] = e0 + excl;
  __syncthreads();
  cnt[tid] = excl;
  __syncthreads();
  for (int e = e0 + tid; e < e1; e += 256){
    unsigned pk = ebuf[e];
    int dl = (int)(pk & 255u);
    int goff = (base_node + dl >= boundary) ? boundary : offA;
    int pos = e0 + atomicAdd(&cnt[dl], 1);
    srcs16[pos] = (unsigned short)((int)(pk >> 8) - goff);
  }
  if (b == 0 && tid == 0) offs[NT_] = E_;
}

// ---------------- permutation layer ----------------
// ez = exp(W + gumbel) = exp(W) / t, t = -log(u).  Incremental addressing, no div.
__global__ __launch_bounds__(512, 8)
void k_perm(const float* __restrict__ W, const float* __restrict__ x,
            float* __restrict__ ypart){
  __shared__ float ez[C_ * ROWP_];          // 32.8 KB
  __shared__ float Ssh[JW_];
  __shared__ float rs[JW_];

  const int bid = blockIdx.x;               // tb*JC_ + jc
  const int tb = bid / JC_;
  const int jc = bid - tb * JC_;
  const int t = tb / B_;
  const int b = tb - t * B_;
  const int j0 = jc * JW_;
  const int xoff = (b * T_ + t) * C_;
  const int tid = threadIdx.x;
  const int w = tid >> 6, l = tid & 63;

  {
    int i = tid / JW_;
    int jj = tid - i * JW_;
    unsigned m = (unsigned)(tb * (C_ * C_) + i * C_ + j0 + jj);  // W idx AND rng ctr
    int la = i * ROWP_ + jj;
    int niter = (C_ * JW_ - tid + 511) >> 9;
    for (int it = 0; it < niter; ++it){
      unsigned bits = rbits(KG.a, KG.b, m);
      float f = __uint_as_float((bits >> 9) | 0x3f800000u) - 1.0f;   // [0,1) exact
      float tneg;
      if (f >= 0.875f){
        float d = 1.0f - f;                  // exact (Sterbenz)
        float p = 0.16666667f;               // -log(1-d) = d*(1+d/2+...+d^5/6)
        p = fmaf(p, d, 0.2f);
        p = fmaf(p, d, 0.25f);
        p = fmaf(p, d, 0.33333333f);
        p = fmaf(p, d, 0.5f);
        p = fmaf(p, d, 1.0f);
        tneg = d * p;
      } else {
        float u = f + 1e-10f;                // uniform(1e-10,1)
        tneg = -__logf(u);
      }
      ez[la] = __expf(W[m]) * __builtin_amdgcn_rcpf(tneg);
      jj += 32;
      int wrap = jj >= JW_;
      jj = wrap ? jj - JW_ : jj;
      m += wrap ? 2592u : 2432u;
      la += wrap ? 525 : 524;
    }
  }
  __syncthreads();

#pragma unroll
  for (int q = 0; q < 5; ++q){
    int jj = w * 5 + q;
    float s = ez[l * ROWP_ + jj] + ez[(l + 64) * ROWP_ + jj] + ez[(l + 128) * ROWP_ + jj]
            + ((l < 8) ? ez[(l + 192) * ROWP_ + jj] : 0.f);
#pragma unroll
    for (int sh = 32; sh >= 1; sh >>= 1) s += __shfl_xor(s, sh, 64);
    if (l == 0) Ssh[jj] = s;
  }
  __syncthreads();
  if (tid < JW_) rs[tid] = x[xoff + j0 + tid] / Ssh[tid];
  __syncthreads();

  if (tid < C_){
    float acc = 0.f;
#pragma unroll 8
    for (int jj = 0; jj < JW_; ++jj)
      acc = fmaf(ez[tid * ROWP_ + jj], rs[jj], acc);
    ypart[jc * NT_ + xoff + tid] = acc;
  }
}

// combine 5 column-chunk partials -> y, plus nonzero stats partials
__global__ __launch_bounds__(256)
void k_ycomb(const float* __restrict__ ypart, float* __restrict__ y,
             float* __restrict__ spart){
  __shared__ float sred[12];
  int n = blockIdx.x * 256 + threadIdx.x;
  float v = 0.f;
#pragma unroll
  for (int jc = 0; jc < JC_; ++jc) v += ypart[jc * NT_ + n];
  y[n] = v;
  float s = 0.f, c = 0.f, q = 0.f;
  if (v != 0.f){ s = v; c = 1.f; q = v * v; }
#pragma unroll
  for (int sh = 32; sh >= 1; sh >>= 1){
    s += __shfl_xor(s, sh, 64);
    c += __shfl_xor(c, sh, 64);
    q += __shfl_xor(q, sh, 64);
  }
  int w = threadIdx.x >> 6, l = threadIdx.x & 63;
  if (l == 0){ sred[w] = s; sred[4 + w] = c; sred[8 + w] = q; }
  __syncthreads();
  if (threadIdx.x == 0){
    spart[blockIdx.x * 3 + 0] = sred[0] + sred[1] + sred[2] + sred[3];
    spart[blockIdx.x * 3 + 1] = sred[4] + sred[5] + sred[6] + sred[7];
    spart[blockIdx.x * 3 + 2] = sred[8] + sred[9] + sred[10] + sred[11];
  }
}

// reduce 625 stat partials -> stats[0] = std/100
__global__ void k_stat2(const float* __restrict__ spart, float* __restrict__ stats){
  __shared__ float sred[12];
  int tid = threadIdx.x;
  float s = 0.f, c = 0.f, q = 0.f;
  for (int i = tid; i < 625; i += 256){
    s += spart[i * 3 + 0];
    c += spart[i * 3 + 1];
    q += spart[i * 3 + 2];
  }
#pragma unroll
  for (int sh = 32; sh >= 1; sh >>= 1){
    s += __shfl_xor(s, sh, 64);
    c += __shfl_xor(c, sh, 64);
    q += __shfl_xor(q, sh, 64);
  }
  int w = tid >> 6, l = tid & 63;
  if (l == 0){ sred[w] = s; sred[4 + w] = c; sred[8 + w] = q; }
  __syncthreads();
  if (tid == 0){
    float S = sred[0] + sred[1] + sred[2] + sred[3];
    float C = sred[4] + sred[5] + sred[6] + sred[7];
    float Q = sred[8] + sred[9] + sred[10] + sred[11];
    float var = (Q - S * S / C) / (C - 1.f);
    stats[0] = sqrtf(var) * 0.01f;
  }
}

__global__ void k_noise(const float* __restrict__ y, const float* __restrict__ stats,
                        float* __restrict__ x0){
  int n = blockIdx.x * 256 + threadIdx.x;
  float v = y[n];
  if (v != 0.0f){ x0[n] = v; return; }
  float scale = stats[0];
  unsigned bits = rbits(KN.a, KN.b, (unsigned)n);
  float f = __uint_as_float((bits >> 9) | 0x3f800000u) - 1.0f;
  float u = f * 2.0f + (-0.99999994f);
  u = fmaxf(-0.99999994f, u);
  float nrm = 1.41421356237f * erfinv_xla(u);
  x0[n] = scale * nrm;
}

// ---------------- fused GAT pass: LDS x, online softmax, 1 native exp/edge-head ----------------
__global__ __launch_bounds__(256)
void k_gat(const float* __restrict__ xin, const float* __restrict__ xres,
           const int* __restrict__ offs, const unsigned short* __restrict__ srcs16,
           const float* __restrict__ gw, const float* __restrict__ asrc,
           const float* __restrict__ adst, const float* __restrict__ gbias,
           const float* __restrict__ bng, const float* __restrict__ bnb,
           const float* __restrict__ bnm, const float* __restrict__ bnv,
           float* __restrict__ xout){
  __shared__ float xsh[N_];                      // whole graph: 40 KB
  int g = blockIdx.x / GB_, c = blockIdx.x - g * GB_;
  int tid = threadIdx.x;
  const float4* xv = (const float4*)(xin + g * N_);
  for (int i = tid; i < N_ / 4; i += 256) ((float4*)xsh)[i] = xv[i];
  __syncthreads();
  if (tid >= GC_) return;

  int nl = c * GC_ + tid;
  int n = g * N_ + nl;
  float xn = xsh[nl];

  float cs[H_], cdxn[H_], wv[H_];
#pragma unroll
  for (int h = 0; h < H_; ++h){
    wv[h] = gw[h];
    cs[h] = wv[h] * asrc[h] * LOG2E_;
    cdxn[h] = wv[h] * adst[h] * xn * LOG2E_;
  }
  float mh[H_], den[H_], num[H_];
#pragma unroll
  for (int h = 0; h < H_; ++h){
    float v = cs[h] * xn + cdxn[h];
    v = fmaxf(v, 0.2f * v);
    mh[h] = v; den[h] = 1.f; num[h] = xn;
  }
  int e0 = offs[n], e1 = offs[n + 1];
  for (int e = e0; e < e1; ++e){
    float xs = xsh[srcs16[e]];
#pragma unroll
    for (int h = 0; h < H_; ++h){
      float v = fmaf(cs[h], xs, cdxn[h]);
      v = fmaxf(v, 0.2f * v);
      float d = v - mh[h];
      float ed = ex2(-fabsf(d));
      bool newmax = d > 0.f;
      float corr = newmax ? ed : 1.f;
      float p    = newmax ? 1.f : ed;
      mh[h] = newmax ? v : mh[h];
      den[h] = fmaf(den[h], corr, p);
      num[h] = fmaf(num[h], corr, p * xs);
    }
  }
  float o = 0.f;
#pragma unroll
  for (int h = 0; h < H_; ++h) o += wv[h] * num[h] * __builtin_amdgcn_rcpf(den[h]);
  o = o * 0.125f + gbias[0];
  o = (o - bnm[0]) / sqrtf(bnv[0] + EPS_) * bng[0] + bnb[0];
  o = o / (1.0f + __expf(-o));
  xout[n] = o + xres[n];
}

// ---------------- final pool + linear + relu ----------------
__global__ __launch_bounds__(256)
void k_pool1(const float* __restrict__ xf, const float* __restrict__ dv,
             float* __restrict__ pmax){
  __shared__ float sred[4];
  int g = blockIdx.x / GB_, c = blockIdx.x - g * GB_;
  int tid = threadIdx.x;
  float m = -INFINITY;
  if (tid < GC_){
    int nl = c * GC_ + tid;
    m = xf[g * N_ + nl] * dv[nl];
  }
#pragma unroll
  for (int s = 32; s >= 1; s >>= 1) m = fmaxf(m, __shfl_xor(m, s, 64));
  int w = tid >> 6, l = tid & 63;
  if (l == 0) sred[w] = m;
  __syncthreads();
  if (tid == 0)
    pmax[blockIdx.x] = fmaxf(fmaxf(sred[0], sred[1]), fmaxf(sred[2], sred[3]));
}

__global__ void k_pool2(const float* __restrict__ pmax, const float* __restrict__ lw,
                        const float* __restrict__ lb, float* __restrict__ out){
  int b = blockIdx.x, l = threadIdx.x;
  float m = (l < GB_) ? pmax[b * GB_ + l] : -INFINITY;
#pragma unroll
  for (int s = 32; s >= 1; s >>= 1) m = fmaxf(m, __shfl_xor(m, s, 64));
  if (l == 0){
    float o = m * lw[0] + lb[0];
    out[b] = (o > 0.f) ? o : 0.f;
  }
}

// ---------------- launch ----------------
extern "C" void kernel_launch(void* const* d_in, const int* in_sizes, int n_in,
                              void* d_out, int out_size, void* d_ws, size_t ws_size,
                              hipStream_t stream){
  const float* x     = (const float*)d_in[0];
  const int*   ei    = (const int*)d_in[1];
  const float* W     = (const float*)d_in[3];
  const float* dv    = (const float*)d_in[4];
  const float* gw    = (const float*)d_in[5];
  const float* asrc  = (const float*)d_in[6];
  const float* adst  = (const float*)d_in[7];
  const float* gbias = (const float*)d_in[8];
  const float* bng   = (const float*)d_in[9];
  const float* bnb   = (const float*)d_in[10];
  const float* bnm   = (const float*)d_in[11];
  const float* bnv   = (const float*)d_in[12];
  const float* lw    = (const float*)d_in[13];
  const float* lb    = (const float*)d_in[14];
  float* out = (float*)d_out;

  char* ws = (char*)d_ws;
  int*            offs   = (int*)           (ws + 0);         // NT_+1 ints
  unsigned short* srcs16 = (unsigned short*)(ws + 640256);    // E_ u16 (10.24 MB)
  int*            cnt    = (int*)           (ws + 10880256);  // EB_*NB_ ints (1.28 MB)
  int*            gscan  = (int*)           (ws + 12160256);  // EB_*NB_ ints (1.28 MB)
  unsigned*       ebuf   = (unsigned*)      (ws + 21120256);  // E_ u32
  float*          ypart  = (float*)         (ws + 21120256);  // aliases ebuf (dead after bcsr)
  float*          y      = (float*)         (ws + 41600256);  // NT_ f32 (x_res)
  float*          x0     = (float*)         (ws + 42240256);  // NT_ f32
  float*          x1     = (float*)         (ws + 42880256);  // NT_ f32
  int*            bsum   = (int*)           (ws + 43520256);  // NB_ ints
  int*            boff   = (int*)           (ws + 43522816);  // NB_+1 ints
  float*          pmax   = (float*)         (ws + 43525376);  // B_*GB_ f32
  float*          stats  = (float*)         (ws + 43527936);  // 8 f32
  float*          spart  = (float*)         (ws + 43527968);  // 625*3 f32
  if (ws_size < (size_t)43535500) return;

  const int* esrc = ei;
  const int* edst = ei + E_;

  k_hist  <<<EB_, ATH_, 0, stream>>>(edst, cnt);
  k_sumb  <<<NB_, 512, 0, stream>>>(cnt, bsum);
  k_scanb <<<1, 256, 0, stream>>>(bsum, boff);
  k_scanc <<<NB_, 512, 0, stream>>>(cnt, boff, gscan);
  k_append<<<EB_, ATH_, 0, stream>>>(esrc, edst, gscan, ebuf);
  k_bcsr  <<<NB_, 256, 0, stream>>>(boff, ebuf, offs, srcs16);
  k_perm  <<<T_ * B_ * JC_, 512, 0, stream>>>(W, x, ypart);
  k_ycomb <<<625, 256, 0, stream>>>(ypart, y, spart);
  k_stat2 <<<1, 256, 0, stream>>>(spart, stats);
  k_noise <<<625, 256, 0, stream>>>(y, stats, x0);
  k_gat<<<B_ * GB_, 256, 0, stream>>>(x0, y, offs, srcs16, gw, asrc, adst, gbias, bng, bnb, bnm, bnv, x1);
  k_gat<<<B_ * GB_, 256, 0, stream>>>(x1, y, offs, srcs16, gw, asrc, adst, gbias, bng, bnb, bnm, bnv, x0);
  k_gat<<<B_ * GB_, 256, 0, stream>>>(x0, y, offs, srcs16, gw, asrc, adst, gbias, bng, bnb, bnm, bnv, x1);
  k_gat<<<B_ * GB_, 256, 0, stream>>>(x1, y, offs, srcs16, gw, asrc, adst, gbias, bng, bnb, bnm, bnv, x0);
  k_pool1 <<<B_ * GB_, 256, 0, stream>>>(x0, dv, pmax);
  k_pool2 <<<B_, 64, 0, stream>>>(pmax, lw, lb, out);
}